// Round 11
// baseline (330.316 us; speedup 1.0000x reference)
//
#include <hip/hip_runtime.h>

typedef unsigned short u16;
typedef u16 u16x4 __attribute__((ext_vector_type(4)));
typedef u16 u16x8 __attribute__((ext_vector_type(8)));
typedef __bf16 bf16x8 __attribute__((ext_vector_type(8)));
typedef float f32x4 __attribute__((ext_vector_type(4)));

#define HB   256    // H
#define NND  127    // nodes per tree
#define BT   512    // trees (batch)
#define KE   300    // E
#define KEP  320    // E padded to 32-multiple
#define VV   50000  // vocab
#define QQ   10     // Q

#define AS1 __attribute__((address_space(1)))
#define AS3 __attribute__((address_space(3)))

__device__ __forceinline__ u16 f2bf(float f) {
    unsigned int u = __builtin_bit_cast(unsigned int, f);
    u += 0x7FFFu + ((u >> 16) & 1u);          // RNE
    return (u16)(u >> 16);
}
__device__ __forceinline__ float bf2f(u16 h) {
    unsigned int u = ((unsigned int)h) << 16;
    return __builtin_bit_cast(float, u);
}
__device__ __forceinline__ float sigm(float x) { return 1.f / (1.f + __expf(-x)); }

__device__ __forceinline__ void glds16(const u16* g, u16* l) {
    __builtin_amdgcn_global_load_lds((const AS1 void*)g, (AS3 void*)l, 16, 0, 0);
}

// ---------- merged prep: vocab conv (15625 blks), W (120), U (96), qD (30) ----------
__global__ __launch_bounds__(256) void k_prep(const float* __restrict__ vec,
                                              u16* __restrict__ vb,
                                              const float* __restrict__ W,
                                              const float* __restrict__ U,
                                              const float* __restrict__ q,
                                              const float* __restrict__ D,
                                              u16* __restrict__ Wb,
                                              u16* __restrict__ Ub,
                                              float* __restrict__ qD) {
    int blk = blockIdx.x;
    if (blk < 15625) {                     // vec: VV rows, K=300 -> Kp=320, u16x4 chunks
        long i = (long)blk * 256 + threadIdx.x;   // 4,000,000 chunks exactly
        int r = (int)(i / 80);
        int c = ((int)(i - (long)r * 80)) * 4;
        u16x4 o = {0, 0, 0, 0};
        if (c < KE) {
            f32x4 x = *(const f32x4*)(vec + (long)r * KE + c);
#pragma unroll
            for (int e = 0; e < 4; ++e) o[e] = f2bf(x[e]);
        }
        *(u16x4*)(vb + i * 4) = o;
    } else if (blk < 15745) {              // W: 768 rows, K=300 -> Kp=320 (40 chunks)
        int i = (blk - 15625) * 256 + threadIdx.x;
        int r = i / 40, c = (i - r * 40) * 8;
        const float* s = W + (long)r * KE + c;
        u16x8 o;
#pragma unroll
        for (int e = 0; e < 8; ++e) o[e] = (c + e < KE) ? f2bf(s[e]) : (u16)0;
        *(u16x8*)(Wb + (long)i * 8) = o;
    } else if (blk < 15841) {              // U: 768 rows, K=Kp=256 (32 chunks)
        int i = (blk - 15745) * 256 + threadIdx.x;
        int r = i / 32, c = (i - r * 32) * 8;
        const float* s = U + (long)r * HB + c;
        u16x8 o;
#pragma unroll
        for (int e = 0; e < 8; ++e) o[e] = f2bf(s[e]);
        *(u16x8*)(Ub + (long)i * 8) = o;
    } else {                               // qD[i] over QQ*768
        int i = (blk - 15841) * 256 + threadIdx.x;
        int qi = i / 768, col = i - qi * 768;
        const float* qr = q + qi * HB;
        const float* dr = D + col * HB;
        float s = 0.f;
        for (int k = 0; k < HB; ++k) s += qr[k] * dr[k];
        qD[i] = s;
    }
}

// ---------- bf16 NT GEMM: global_load_lds(16B), 128x128 tile ----------
// Depth-3 pipeline, 4 LDS buffers, counted vmcnt (T4) — best measured variant (R6), frozen.
// C[M,N] = A[M,K] * B[N,K]^T ; A,B bf16 row-major, K/32 = nk >= 4, N % 128 == 0.
// optional A-row map: global_row = (r>>cnlog2)*127 + cstart + (r & ((1<<cnlog2)-1))
template <bool STORE_BF16>
__global__ __launch_bounds__(256) void k_gemm(const u16* __restrict__ A,
                                              const u16* __restrict__ B,
                                              void* __restrict__ C,
                                              int M, int N, int K,
                                              int map_cnlog2, int map_cstart) {
    __shared__ u16 As[4][128 * 32];
    __shared__ u16 Bs[4][128 * 32];

    // bijective XCD-chunked swizzle (m204) on linear bid, x-inner
    int nwg = gridDim.x * gridDim.y;
    int orig = blockIdx.y * gridDim.x + blockIdx.x;
    int qq = nwg >> 3, rr = nwg & 7;
    int xcd = orig & 7, cidx = orig >> 3;
    int wg = (xcd < rr ? xcd * (qq + 1) : rr * (qq + 1) + (xcd - rr) * qq) + cidx;
    int bx = wg % gridDim.x, by = wg / gridDim.x;
    int row0 = by * 128, col0 = bx * 128;

    int t = threadIdx.x, lane = t & 63, w = t >> 6;
    int wr = w >> 1, wc = w & 1;

    // staging geometry: per wave-issue, 64 lanes x 16B = 16 rows x 32 u16
    int cof = (lane & 3) * 8;            // u16 col offset
    int rin = lane >> 2;                 // 0..15 row within issue
    int ar0 = row0 + w * 32 + rin;
    int ar1 = ar0 + 16;
    auto mapfn = [&](int r) {
        if (r > M - 1) r = M - 1;
        if (map_cnlog2 >= 0) {
            int bt = r >> map_cnlog2;
            int of = r & ((1 << map_cnlog2) - 1);
            r = bt * NND + map_cstart + of;
        }
        return r;
    };
    const u16* aS0 = A + (long)mapfn(ar0) * K + cof;
    const u16* aS1 = A + (long)mapfn(ar1) * K + cof;
    const u16* bS0 = B + (long)(col0 + w * 32 + rin) * K + cof;
    const u16* bS1 = bS0 + 16L * K;
    int dof0 = (w * 32) * 32;
    int dof1 = (w * 32 + 16) * 32;

    f32x4 acc[4][4];
#pragma unroll
    for (int m = 0; m < 4; ++m)
#pragma unroll
        for (int n = 0; n < 4; ++n) acc[m][n] = f32x4{0.f, 0.f, 0.f, 0.f};

    int arl = wr * 64 + (lane & 15);
    int brl = wc * 64 + (lane & 15);
    int kk = (lane >> 4) * 8;

    auto stage = [&](int sel, int ko) {
        glds16(aS0 + ko, &As[sel][dof0]);
        glds16(aS1 + ko, &As[sel][dof1]);
        glds16(bS0 + ko, &Bs[sel][dof0]);
        glds16(bS1 + ko, &Bs[sel][dof1]);
    };
    auto compute = [&](int sel) {
        bf16x8 af[4], bfr[4];
#pragma unroll
        for (int m = 0; m < 4; ++m)
            af[m] = *(const bf16x8*)&As[sel][(arl + m * 16) * 32 + kk];
#pragma unroll
        for (int n = 0; n < 4; ++n)
            bfr[n] = *(const bf16x8*)&Bs[sel][(brl + n * 16) * 32 + kk];
#pragma unroll
        for (int m = 0; m < 4; ++m)
#pragma unroll
            for (int n = 0; n < 4; ++n)
                acc[m][n] = __builtin_amdgcn_mfma_f32_16x16x32_bf16(af[m], bfr[n], acc[m][n], 0, 0, 0);
    };

    int nk = K >> 5;                     // 8 or 10 here (>= 4 required)
    stage(0, 0); stage(1, 32); stage(2, 64);     // 12 loads/wave in flight
    for (int kt = 0; kt < nk - 3; ++kt) {
        asm volatile("s_waitcnt vmcnt(8)" ::: "memory");
        __builtin_amdgcn_s_barrier();
        __builtin_amdgcn_sched_barrier(0);
        compute(kt & 3);
        stage((kt + 3) & 3, (kt + 3) * 32);
    }
    asm volatile("s_waitcnt vmcnt(8)" ::: "memory");
    __builtin_amdgcn_s_barrier();
    __builtin_amdgcn_sched_barrier(0);
    compute((nk - 3) & 3);
    asm volatile("s_waitcnt vmcnt(4)" ::: "memory");
    __builtin_amdgcn_s_barrier();
    __builtin_amdgcn_sched_barrier(0);
    compute((nk - 2) & 3);
    asm volatile("s_waitcnt vmcnt(0)" ::: "memory");
    __builtin_amdgcn_s_barrier();
    __builtin_amdgcn_sched_barrier(0);
    compute((nk - 1) & 3);

    int crow = row0 + wr * 64 + (lane >> 4) * 4;
    int ccol = col0 + wc * 64 + (lane & 15);
#pragma unroll
    for (int m = 0; m < 4; ++m) {
#pragma unroll
        for (int n = 0; n < 4; ++n) {
#pragma unroll
            for (int j = 0; j < 4; ++j) {
                int r = crow + m * 16 + j;
                int c = ccol + n * 16;
                if (r < M) {
                    if (STORE_BF16) ((u16*)C)[(long)r * N + c] = f2bf(acc[m][n][j]);
                    else            ((float*)C)[(long)r * N + c] = acc[m][n][j];
                }
            }
        }
    }
}

// ---------- leaves, vectorized: one wave per leaf, 4 j per lane ----------
__global__ __launch_bounds__(256) void k_leaf(const int* __restrict__ tok,
                                              const u16* __restrict__ vW,
                                              const float* __restrict__ qD,
                                              const float* __restrict__ b,
                                              u16* __restrict__ h) {
    int w = threadIdx.x >> 6, t = threadIdx.x & 63;
    int leaf = blockIdx.x * 4 + w;             // 0..32767
    int j = t * 4;
    int bt = leaf >> 6, li = leaf & 63;        // 64 leaves per tree
    int row = bt * NND + 63 + li;
    long vwb = (long)tok[row] * 768;
    u16x4 vi = *(const u16x4*)(vW + vwb + 256 + j);
    u16x4 vu = *(const u16x4*)(vW + vwb + 512 + j);
    f32x4 qi = *(const f32x4*)(qD + 9 * 768 + 256 + j);
    f32x4 qu = *(const f32x4*)(qD + 9 * 768 + 512 + j);
    f32x4 bi = *(const f32x4*)(b + 256 + j);
    f32x4 bu = *(const f32x4*)(b + 512 + j);
    u16x4 o;
#pragma unroll
    for (int e = 0; e < 4; ++e) {
        float ii = bf2f(vi[e]) + qi[e] + bi[e];
        float uu = bf2f(vu[e]) + qu[e] + bu[e];
        o[e] = f2bf(tanhf(sigm(ii) * tanhf(uu)));
    }
    *(u16x4*)(h + (long)row * HB + j) = o;
}

// ---------- lv1 update, vectorized: one wave per parent, 4 j per lane ----------
__global__ __launch_bounds__(256) void k_update(const int* __restrict__ tok,
                                                const int* __restrict__ dep,
                                                const u16* __restrict__ vW,
                                                const float* __restrict__ qD,
                                                const float* __restrict__ b,
                                                const u16* __restrict__ g,
                                                u16* __restrict__ h,
                                                int pstart, int pnl) {
    int w = threadIdx.x >> 6, t = threadIdx.x & 63;
    int pi = blockIdx.x * 4 + w;
    int j = t * 4;
    int bt = pi >> pnl, po = pi & ((1 << pnl) - 1);
    int pl = pstart + po;
    int gp  = bt * NND + pl;
    int gc1 = bt * NND + 2 * pl + 1, gc2 = gc1 + 1;
    long cc1 = (long)((bt << (pnl + 1)) + 2 * po) * 768;  // g rows of the two children
    long cc2 = cc1 + 768;
    long vwb = (long)tok[gp] * 768;
    int d1 = dep[gc1] * 768, d2 = dep[gc2] * 768;
    u16x4 vf  = *(const u16x4*)(vW + vwb + j);
    u16x4 vi  = *(const u16x4*)(vW + vwb + 256 + j);
    u16x4 vu  = *(const u16x4*)(vW + vwb + 512 + j);
    u16x4 gf1 = *(const u16x4*)(g + cc1 + j);
    u16x4 gf2 = *(const u16x4*)(g + cc2 + j);
    u16x4 gi1 = *(const u16x4*)(g + cc1 + 256 + j);
    u16x4 gi2 = *(const u16x4*)(g + cc2 + 256 + j);
    u16x4 gu1 = *(const u16x4*)(g + cc1 + 512 + j);
    u16x4 gu2 = *(const u16x4*)(g + cc2 + 512 + j);
    f32x4 qf1 = *(const f32x4*)(qD + d1 + j);
    f32x4 qf2 = *(const f32x4*)(qD + d2 + j);
    f32x4 qi1 = *(const f32x4*)(qD + d1 + 256 + j);
    f32x4 qi2 = *(const f32x4*)(qD + d2 + 256 + j);
    f32x4 qu1 = *(const f32x4*)(qD + d1 + 512 + j);
    f32x4 qu2 = *(const f32x4*)(qD + d2 + 512 + j);
    f32x4 bf_ = *(const f32x4*)(b + j);
    f32x4 bi_ = *(const f32x4*)(b + 256 + j);
    f32x4 bu_ = *(const f32x4*)(b + 512 + j);
    u16x4 h1v = *(const u16x4*)(h + (long)gc1 * HB + j);
    u16x4 h2v = *(const u16x4*)(h + (long)gc2 * HB + j);
    u16x4 resb;
#pragma unroll
    for (int e = 0; e < 4; ++e) {
        float xf = bf2f(vf[e]) + bf_[e];
        float f1 = sigm(xf + bf2f(gf1[e]) + qf1[e]);
        float f2 = sigm(xf + bf2f(gf2[e]) + qf2[e]);
        float ii = bf2f(vi[e]) + bf2f(gi1[e]) + bf2f(gi2[e]) + qi1[e] + qi2[e] + bi_[e];
        float uu = bf2f(vu[e]) + bf2f(gu1[e]) + bf2f(gu2[e]) + qu1[e] + qu2[e] + bu_[e];
        float hn = tanhf(sigm(ii) * tanhf(uu) + f1 * bf2f(h1v[e]) + f2 * bf2f(h2v[e]));
        resb[e] = f2bf(hn);
    }
    *(u16x4*)(h + (long)gp * HB + j) = resb;
}

// ---------- fused tail: levels 2..6, one tree per block ----------
// Per level: GEMM g = h_children @ U^T (MFMA, LDS-staged U K-slices, 2 N-halves),
// epilogue -> LDS gf (f-part per child) + giu (sibling-pair-summed i/u per parent),
// then in-block update -> parent h (global) / root -> out (fp32).
__global__ __launch_bounds__(256) void k_tail(const int* __restrict__ tok,
                                              const int* __restrict__ dep,
                                              const u16* __restrict__ vW,
                                              const float* __restrict__ qD,
                                              const float* __restrict__ b,
                                              const u16* __restrict__ Ub,
                                              u16* __restrict__ h,
                                              float* __restrict__ out) {
    __shared__ u16 Us[384 * 32];    // 24 KB: U K-slice for one N-half
    __shared__ u16 Ast[32 * 32];    // 2 KB: children-h K-slice
    __shared__ u16 gf[32 * 256];    // 16 KB: f-part, per child row
    __shared__ u16 giu[16 * 512];   // 16 KB: pair-summed i/u, per parent row

    int bt = blockIdx.x;
    int t = threadIdx.x, lane = t & 63, w = t >> 6;
    int rin = lane >> 2, cof = (lane & 3) * 8;
    int kk = (lane >> 4) * 8;

    for (int lv = 2; lv <= 6; ++lv) {
        int pnl = 6 - lv;
        int pn = 1 << pnl;                // parents per tree: 16,8,4,2,1
        int cn = pn << 1;                 // children: 32,16,8,4,2
        int pstart = pn - 1, cstart = cn - 1;
        int mt_w, ncb, nf_cnt;
        if (cn == 32) { mt_w = w & 1; ncb = (w >> 1) * 192; nf_cnt = 12; }
        else          { mt_w = 0;     ncb = w * 96;         nf_cnt = 6;  }

        for (int pass = 0; pass < 2; ++pass) {
            f32x4 acc[12];
#pragma unroll
            for (int n = 0; n < 12; ++n) acc[n] = f32x4{0.f, 0.f, 0.f, 0.f};

            for (int ks = 0; ks < 8; ++ks) {
                __syncthreads();                    // prior Us/Ast reads done
#pragma unroll
                for (int is = 0; is < 6; ++is) {    // stage U N-half K-slice: 384x32
                    int nrow = is * 64 + w * 16 + rin;
                    glds16(Ub + (long)(pass * 384 + nrow) * HB + ks * 32 + cof,
                           &Us[(is * 64 + w * 16) * 32]);
                }
                if (w < 2) {                        // stage children h K-slice: 32x32
                    int r = w * 16 + rin;
                    int rc = r < cn ? r : cn - 1;
                    glds16(h + (long)(bt * NND + cstart + rc) * HB + ks * 32 + cof,
                           &Ast[(w * 16) * 32]);
                }
                __syncthreads();                    // drains glds -> LDS ready
                bf16x8 af = *(const bf16x8*)&Ast[(mt_w * 16 + (lane & 15)) * 32 + kk];
#pragma unroll
                for (int nf = 0; nf < 12; ++nf) {
                    if (nf < nf_cnt) {
                        bf16x8 bfr = *(const bf16x8*)&Us[(ncb + nf * 16 + (lane & 15)) * 32 + kk];
                        acc[nf] = __builtin_amdgcn_mfma_f32_16x16x32_bf16(af, bfr, acc[nf], 0, 0, 0);
                    }
                }
            }
            // epilogue: gf / pair-summed giu (regions disjoint from Us/Ast -> no barrier needed)
            int crow = mt_w * 16 + (lane >> 4) * 4;
#pragma unroll
            for (int nf = 0; nf < 12; ++nf) {
                if (nf < nf_cnt && crow < cn) {
                    int gcol = pass * 384 + ncb + nf * 16 + (lane & 15);
                    if (gcol < 256) {
#pragma unroll
                        for (int j = 0; j < 4; ++j)
                            gf[(crow + j) * 256 + gcol] = f2bf(acc[nf][j]);
                    } else {
                        int ci = gcol - 256;
                        giu[(crow >> 1) * 512 + ci]       = f2bf(acc[nf][0] + acc[nf][1]);
                        giu[((crow >> 1) + 1) * 512 + ci] = f2bf(acc[nf][2] + acc[nf][3]);
                    }
                }
            }
        }
        __syncthreads();                            // g complete

        // update: pn parents x 256 cols over 256 threads -> pn cols/thread
        int tpc = 256 / pn;
        int p = t / tpc;
        int c0 = (t % tpc) * pn;
        int gp  = bt * NND + pstart + p;
        int gc1 = bt * NND + cstart + 2 * p, gc2 = gc1 + 1;
        long vwb = (long)tok[gp] * 768;
        int d1 = dep[gc1] * 768, d2 = dep[gc2] * 768;
        int c1l = 2 * p, c2l = 2 * p + 1;
        for (int cc = 0; cc < pn; ++cc) {
            int col = c0 + cc;
            float xf = bf2f(vW[vwb + col]) + b[col];
            float f1 = sigm(xf + bf2f(gf[c1l * 256 + col]) + qD[d1 + col]);
            float f2 = sigm(xf + bf2f(gf[c2l * 256 + col]) + qD[d2 + col]);
            float ii = bf2f(vW[vwb + 256 + col]) + bf2f(giu[p * 512 + col])
                     + qD[d1 + 256 + col] + qD[d2 + 256 + col] + b[256 + col];
            float uu = bf2f(vW[vwb + 512 + col]) + bf2f(giu[p * 512 + 256 + col])
                     + qD[d1 + 512 + col] + qD[d2 + 512 + col] + b[512 + col];
            float h1 = bf2f(h[(long)gc1 * HB + col]);
            float h2 = bf2f(h[(long)gc2 * HB + col]);
            float hn = tanhf(sigm(ii) * tanhf(uu) + f1 * h1 + f2 * h2);
            if (lv == 6) out[(long)bt * HB + col] = hn;
            else         h[(long)gp * HB + col] = f2bf(hn);
        }
        __syncthreads();                            // update h visible before next level stages
    }
}

extern "C" void kernel_launch(void* const* d_in, const int* in_sizes, int n_in,
                              void* d_out, int out_size, void* d_ws, size_t ws_size,
                              hipStream_t stream) {
    const int*   tok = (const int*)d_in[0];
    const int*   dep = (const int*)d_in[1];
    const float* vec = (const float*)d_in[2];
    const float* q   = (const float*)d_in[3];
    const float* W   = (const float*)d_in[4];
    const float* U   = (const float*)d_in[5];
    const float* D   = (const float*)d_in[6];
    const float* b   = (const float*)d_in[7];

    char* ws = (char*)d_ws;
    size_t off = 0;
    auto alloc = [&](size_t bytes) {
        void* p = ws + off;
        off += (bytes + 255) & ~(size_t)255;
        return p;
    };
    float* qD = (float*)alloc((size_t)QQ * 768 * 4);
    u16*   vb = (u16*)alloc((size_t)VV * KEP * 2);
    u16*   Wb = (u16*)alloc((size_t)768 * KEP * 2);
    u16*   Ub = (u16*)alloc((size_t)768 * HB * 2);
    u16*   vW = (u16*)alloc((size_t)VV * 768 * 2);
    u16*   h  = (u16*)alloc((size_t)BT * NND * HB * 2);
    u16*   g  = (u16*)alloc((size_t)BT * 64 * 768 * 2);
    if (ws_size < off) return;  // ~177 MiB needed; zero output signals ws too small

    // 1) prep: vocab conv + W/U conv + qD
    k_prep<<<15871, 256, 0, stream>>>(vec, vb, W, U, q, D, Wb, Ub, qD);

    // 2) vW = (idx2vec @ W.T) as bf16, vocab-wide
    k_gemm<true><<<dim3(6, (VV + 127) / 128), 256, 0, stream>>>(
        vb, Wb, vW, VV, 768, KEP, -1, 0);

    // 3) leaves
    k_leaf<<<BT * 64 / 4, 256, 0, stream>>>(tok, vW, qD, b, h);

    // 4) lv1 GEMM: g[32768,768] = h_leaf @ U.T  (cnl=6, cstart=63)
    k_gemm<true><<<dim3(6, 256), 256, 0, stream>>>(
        h, Ub, g, BT * 64, 768, HB, 6, 63);

    // 5) lv1 update (pstart=31, pnl=5)
    k_update<<<BT * 32 / 4, 256, 0, stream>>>(tok, dep, vW, qD, b, g, h, 31, 5);

    // 6) fused levels 2..6 + output
    k_tail<<<BT, 256, 0, stream>>>(tok, dep, vW, qD, b, Ub, h, (float*)d_out);
}

// Round 12
// 250.027 us; speedup vs baseline: 1.3211x; 1.3211x over previous
//
#include <hip/hip_runtime.h>

typedef unsigned short u16;
typedef u16 u16x4 __attribute__((ext_vector_type(4)));
typedef u16 u16x8 __attribute__((ext_vector_type(8)));
typedef __bf16 bf16x8 __attribute__((ext_vector_type(8)));
typedef float f32x4 __attribute__((ext_vector_type(4)));

#define HB   256    // H
#define NND  127    // nodes per tree
#define BT   512    // trees (batch)
#define KE   300    // E
#define KEP  320    // E padded to 32-multiple
#define VV   50000  // vocab
#define QQ   10     // Q

#define AS1 __attribute__((address_space(1)))
#define AS3 __attribute__((address_space(3)))

__device__ __forceinline__ u16 f2bf(float f) {
    unsigned int u = __builtin_bit_cast(unsigned int, f);
    u += 0x7FFFu + ((u >> 16) & 1u);          // RNE
    return (u16)(u >> 16);
}
__device__ __forceinline__ float bf2f(u16 h) {
    unsigned int u = ((unsigned int)h) << 16;
    return __builtin_bit_cast(float, u);
}
__device__ __forceinline__ float sigm(float x) { return 1.f / (1.f + __expf(-x)); }

__device__ __forceinline__ void glds16(const u16* g, u16* l) {
    __builtin_amdgcn_global_load_lds((const AS1 void*)g, (AS3 void*)l, 16, 0, 0);
}

// ---------- merged prep: vocab conv (15625 blks), W (120), U (96), qD (30) ----------
__global__ __launch_bounds__(256) void k_prep(const float* __restrict__ vec,
                                              u16* __restrict__ vb,
                                              const float* __restrict__ W,
                                              const float* __restrict__ U,
                                              const float* __restrict__ q,
                                              const float* __restrict__ D,
                                              u16* __restrict__ Wb,
                                              u16* __restrict__ Ub,
                                              float* __restrict__ qD) {
    int blk = blockIdx.x;
    if (blk < 15625) {                     // vec: VV rows, K=300 -> Kp=320, u16x4 chunks
        long i = (long)blk * 256 + threadIdx.x;   // 4,000,000 chunks exactly
        int r = (int)(i / 80);
        int c = ((int)(i - (long)r * 80)) * 4;
        u16x4 o = {0, 0, 0, 0};
        if (c < KE) {
            f32x4 x = *(const f32x4*)(vec + (long)r * KE + c);
#pragma unroll
            for (int e = 0; e < 4; ++e) o[e] = f2bf(x[e]);
        }
        *(u16x4*)(vb + i * 4) = o;
    } else if (blk < 15745) {              // W: 768 rows, K=300 -> Kp=320 (40 chunks)
        int i = (blk - 15625) * 256 + threadIdx.x;
        int r = i / 40, c = (i - r * 40) * 8;
        const float* s = W + (long)r * KE + c;
        u16x8 o;
#pragma unroll
        for (int e = 0; e < 8; ++e) o[e] = (c + e < KE) ? f2bf(s[e]) : (u16)0;
        *(u16x8*)(Wb + (long)i * 8) = o;
    } else if (blk < 15841) {              // U: 768 rows, K=Kp=256 (32 chunks)
        int i = (blk - 15745) * 256 + threadIdx.x;
        int r = i / 32, c = (i - r * 32) * 8;
        const float* s = U + (long)r * HB + c;
        u16x8 o;
#pragma unroll
        for (int e = 0; e < 8; ++e) o[e] = f2bf(s[e]);
        *(u16x8*)(Ub + (long)i * 8) = o;
    } else {                               // qD[i] over QQ*768
        int i = (blk - 15841) * 256 + threadIdx.x;
        int qi = i / 768, col = i - qi * 768;
        const float* qr = q + qi * HB;
        const float* dr = D + col * HB;
        float s = 0.f;
        for (int k = 0; k < HB; ++k) s += qr[k] * dr[k];
        qD[i] = s;
    }
}

// ---------- bf16 NT GEMM: global_load_lds(16B), 128x128 tile ----------
// Depth-3 pipeline, 4 LDS buffers, counted vmcnt (T4) — frozen (R6). Used for vW only.
__global__ __launch_bounds__(256) void k_gemm(const u16* __restrict__ A,
                                              const u16* __restrict__ B,
                                              u16* __restrict__ C,
                                              int M, int N, int K) {
    __shared__ u16 As[4][128 * 32];
    __shared__ u16 Bs[4][128 * 32];

    // bijective XCD-chunked swizzle (m204) on linear bid, x-inner
    int nwg = gridDim.x * gridDim.y;
    int orig = blockIdx.y * gridDim.x + blockIdx.x;
    int qq = nwg >> 3, rr = nwg & 7;
    int xcd = orig & 7, cidx = orig >> 3;
    int wg = (xcd < rr ? xcd * (qq + 1) : rr * (qq + 1) + (xcd - rr) * qq) + cidx;
    int bx = wg % gridDim.x, by = wg / gridDim.x;
    int row0 = by * 128, col0 = bx * 128;

    int t = threadIdx.x, lane = t & 63, w = t >> 6;
    int wr = w >> 1, wc = w & 1;

    int cof = (lane & 3) * 8;            // u16 col offset
    int rin = lane >> 2;                 // 0..15 row within issue
    int ar0 = row0 + w * 32 + rin; if (ar0 > M - 1) ar0 = M - 1;
    int ar1 = row0 + w * 32 + 16 + rin; if (ar1 > M - 1) ar1 = M - 1;
    const u16* aS0 = A + (long)ar0 * K + cof;
    const u16* aS1 = A + (long)ar1 * K + cof;
    const u16* bS0 = B + (long)(col0 + w * 32 + rin) * K + cof;
    const u16* bS1 = bS0 + 16L * K;
    int dof0 = (w * 32) * 32;
    int dof1 = (w * 32 + 16) * 32;

    f32x4 acc[4][4];
#pragma unroll
    for (int m = 0; m < 4; ++m)
#pragma unroll
        for (int n = 0; n < 4; ++n) acc[m][n] = f32x4{0.f, 0.f, 0.f, 0.f};

    int arl = wr * 64 + (lane & 15);
    int brl = wc * 64 + (lane & 15);
    int kk = (lane >> 4) * 8;

    auto stage = [&](int sel, int ko) {
        glds16(aS0 + ko, &As[sel][dof0]);
        glds16(aS1 + ko, &As[sel][dof1]);
        glds16(bS0 + ko, &Bs[sel][dof0]);
        glds16(bS1 + ko, &Bs[sel][dof1]);
    };
    auto compute = [&](int sel) {
        bf16x8 af[4], bfr[4];
#pragma unroll
        for (int m = 0; m < 4; ++m)
            af[m] = *(const bf16x8*)&As[sel][(arl + m * 16) * 32 + kk];
#pragma unroll
        for (int n = 0; n < 4; ++n)
            bfr[n] = *(const bf16x8*)&Bs[sel][(brl + n * 16) * 32 + kk];
#pragma unroll
        for (int m = 0; m < 4; ++m)
#pragma unroll
            for (int n = 0; n < 4; ++n)
                acc[m][n] = __builtin_amdgcn_mfma_f32_16x16x32_bf16(af[m], bfr[n], acc[m][n], 0, 0, 0);
    };

    int nk = K >> 5;
    stage(0, 0); stage(1, 32); stage(2, 64);
    for (int kt = 0; kt < nk - 3; ++kt) {
        asm volatile("s_waitcnt vmcnt(8)" ::: "memory");
        __builtin_amdgcn_s_barrier();
        __builtin_amdgcn_sched_barrier(0);
        compute(kt & 3);
        stage((kt + 3) & 3, (kt + 3) * 32);
    }
    asm volatile("s_waitcnt vmcnt(8)" ::: "memory");
    __builtin_amdgcn_s_barrier();
    __builtin_amdgcn_sched_barrier(0);
    compute((nk - 3) & 3);
    asm volatile("s_waitcnt vmcnt(4)" ::: "memory");
    __builtin_amdgcn_s_barrier();
    __builtin_amdgcn_sched_barrier(0);
    compute((nk - 2) & 3);
    asm volatile("s_waitcnt vmcnt(0)" ::: "memory");
    __builtin_amdgcn_s_barrier();
    __builtin_amdgcn_sched_barrier(0);
    compute((nk - 1) & 3);

    int crow = row0 + wr * 64 + (lane >> 4) * 4;
    int ccol = col0 + wc * 64 + (lane & 15);
#pragma unroll
    for (int m = 0; m < 4; ++m) {
#pragma unroll
        for (int n = 0; n < 4; ++n) {
#pragma unroll
            for (int j = 0; j < 4; ++j) {
                int r = crow + m * 16 + j;
                if (r < M) C[(long)r * N + ccol + n * 16] = f2bf(acc[m][n][j]);
            }
        }
    }
}

// ---------- leaves, vectorized: one wave per leaf, 4 j per lane ----------
__global__ __launch_bounds__(256) void k_leaf(const int* __restrict__ tok,
                                              const u16* __restrict__ vW,
                                              const float* __restrict__ qD,
                                              const float* __restrict__ b,
                                              u16* __restrict__ h) {
    int w = threadIdx.x >> 6, t = threadIdx.x & 63;
    int leaf = blockIdx.x * 4 + w;             // 0..32767
    int j = t * 4;
    int bt = leaf >> 6, li = leaf & 63;        // 64 leaves per tree
    int row = bt * NND + 63 + li;
    long vwb = (long)tok[row] * 768;
    u16x4 vi = *(const u16x4*)(vW + vwb + 256 + j);
    u16x4 vu = *(const u16x4*)(vW + vwb + 512 + j);
    f32x4 qi = *(const f32x4*)(qD + 9 * 768 + 256 + j);
    f32x4 qu = *(const f32x4*)(qD + 9 * 768 + 512 + j);
    f32x4 bi = *(const f32x4*)(b + 256 + j);
    f32x4 bu = *(const f32x4*)(b + 512 + j);
    u16x4 o;
#pragma unroll
    for (int e = 0; e < 4; ++e) {
        float ii = bf2f(vi[e]) + qi[e] + bi[e];
        float uu = bf2f(vu[e]) + qu[e] + bu[e];
        o[e] = f2bf(tanhf(sigm(ii) * tanhf(uu)));
    }
    *(u16x4*)(h + (long)row * HB + j) = o;
}

// ---------- fused per-level GEMM + update ----------
// Block (512 thr / 8 waves) owns 64 child rows x all 768 g-cols; 32 parents updated
// in-block from fp32 accumulators (col-strip ownership: wave w owns output cols
// [w*32,w*32+32) as fragments f@c, i@256+c, u@512+c -> update is lane-local).
__global__ __launch_bounds__(512) void k_lvl(const int* __restrict__ tok,
                                             const int* __restrict__ dep,
                                             const u16* __restrict__ vW,
                                             const float* __restrict__ qD,
                                             const float* __restrict__ b,
                                             const u16* __restrict__ Ub,
                                             u16* __restrict__ h,
                                             float* __restrict__ out,
                                             int cnl) {
    __shared__ u16 Bs[768 * 32];     // 48 KB: U K-slice
    __shared__ u16 As[64 * 32];      // 4 KB: children-h K-slice

    int cn = 1 << cnl, cstart = cn - 1;
    int pnl = cnl - 1, pn = 1 << pnl, pstart = pn - 1;
    int blk = blockIdx.x;
    int t = threadIdx.x, lane = t & 63, w = t >> 6;
    int rin = lane >> 2, cof = (lane & 3) * 8;
    int kk = (lane >> 4) * 8;
    int l15 = lane & 15;

    // A source: child rows blk*64 + w*16 + rin (waves 0-3)
    int rhA = blk * 64 + w * 16 + rin;
    int btA = rhA >> cnl;
    const u16* aSrc = h + (long)(btA * NND + cstart + (rhA & (cn - 1))) * HB + cof;
    // B source: U rows is*128 + w*16 + rin
    const u16* bSrc = Ub + (long)(w * 16 + rin) * HB + cof;

    f32x4 acc[4][6];
#pragma unroll
    for (int m = 0; m < 4; ++m)
#pragma unroll
        for (int f = 0; f < 6; ++f) acc[m][f] = f32x4{0.f, 0.f, 0.f, 0.f};

    for (int ks = 0; ks < 8; ++ks) {
        __syncthreads();                 // previous-step readers done
        if (w < 4) glds16(aSrc + ks * 32, &As[(w * 16) * 32]);
#pragma unroll
        for (int is = 0; is < 6; ++is)
            glds16(bSrc + (long)is * 128 * HB + ks * 32, &Bs[(is * 128 + w * 16) * 32]);
        __syncthreads();                 // glds drained (vmcnt 0 at barrier)
        bf16x8 af[4], bf[6];
#pragma unroll
        for (int m = 0; m < 4; ++m)
            af[m] = *(const bf16x8*)&As[(m * 16 + l15) * 32 + kk];
#pragma unroll
        for (int f = 0; f < 6; ++f) {
            int part = f >> 1, within = f & 1;
            int brow = part * 256 + w * 32 + within * 16 + l15;
            bf[f] = *(const bf16x8*)&Bs[brow * 32 + kk];
        }
#pragma unroll
        for (int m = 0; m < 4; ++m)
#pragma unroll
            for (int f = 0; f < 6; ++f)
                acc[m][f] = __builtin_amdgcn_mfma_f32_16x16x32_bf16(af[m], bf[f], acc[m][f], 0, 0, 0);
    }

    // ---- in-block update: 2 output cols/lane x 4 m x 2 parent-pairs ----
#pragma unroll
    for (int m = 0; m < 4; ++m) {
        int r0 = m * 16 + (lane >> 4) * 4;     // first of 4 child rows in this lane
#pragma unroll
        for (int qp = 0; qp < 2; ++qp) {
            int ca = r0 + 2 * qp;              // local child row (even)
            int rh = blk * 64 + ca;            // global child index (level-local)
            int pi = rh >> 1;
            int bt = pi >> pnl;
            int po = pi & (pn - 1);
            int gp  = bt * NND + pstart + po;
            int gc1 = bt * NND + cstart + (rh & (cn - 1));
            int gc2 = gc1 + 1;
            long vwb = (long)tok[gp] * 768;
            int d1 = dep[gc1] * 768, d2 = dep[gc2] * 768;
#pragma unroll
            for (int within = 0; within < 2; ++within) {
                int c = w * 32 + within * 16 + l15;
                float fe1 = acc[m][within][2 * qp];
                float fe2 = acc[m][within][2 * qp + 1];
                float gis = acc[m][2 + within][2 * qp] + acc[m][2 + within][2 * qp + 1];
                float gus = acc[m][4 + within][2 * qp] + acc[m][4 + within][2 * qp + 1];
                float xf = bf2f(vW[vwb + c]) + b[c];
                float f1 = sigm(xf + fe1 + qD[d1 + c]);
                float f2 = sigm(xf + fe2 + qD[d2 + c]);
                float ii = bf2f(vW[vwb + 256 + c]) + gis
                         + qD[d1 + 256 + c] + qD[d2 + 256 + c] + b[256 + c];
                float uu = bf2f(vW[vwb + 512 + c]) + gus
                         + qD[d1 + 512 + c] + qD[d2 + 512 + c] + b[512 + c];
                float h1 = bf2f(h[(long)gc1 * HB + c]);
                float h2 = bf2f(h[(long)gc2 * HB + c]);
                float hn = tanhf(sigm(ii) * tanhf(uu) + f1 * h1 + f2 * h2);
                if (out) out[(long)bt * HB + c] = hn;        // lv6: pn==1, pi==bt
                else     h[(long)gp * HB + c] = f2bf(hn);
            }
        }
    }
}

extern "C" void kernel_launch(void* const* d_in, const int* in_sizes, int n_in,
                              void* d_out, int out_size, void* d_ws, size_t ws_size,
                              hipStream_t stream) {
    const int*   tok = (const int*)d_in[0];
    const int*   dep = (const int*)d_in[1];
    const float* vec = (const float*)d_in[2];
    const float* q   = (const float*)d_in[3];
    const float* W   = (const float*)d_in[4];
    const float* U   = (const float*)d_in[5];
    const float* D   = (const float*)d_in[6];
    const float* b   = (const float*)d_in[7];

    char* ws = (char*)d_ws;
    size_t off = 0;
    auto alloc = [&](size_t bytes) {
        void* p = ws + off;
        off += (bytes + 255) & ~(size_t)255;
        return p;
    };
    float* qD = (float*)alloc((size_t)QQ * 768 * 4);
    u16*   vb = (u16*)alloc((size_t)VV * KEP * 2);
    u16*   Wb = (u16*)alloc((size_t)768 * KEP * 2);
    u16*   Ub = (u16*)alloc((size_t)768 * HB * 2);
    u16*   vW = (u16*)alloc((size_t)VV * 768 * 2);
    u16*   h  = (u16*)alloc((size_t)BT * NND * HB * 2);
    if (ws_size < off) return;  // ~142 MiB needed; zero output signals ws too small

    // 1) prep: vocab conv + W/U conv + qD
    k_prep<<<15871, 256, 0, stream>>>(vec, vb, W, U, q, D, Wb, Ub, qD);

    // 2) vW = (idx2vec @ W.T) as bf16, vocab-wide
    k_gemm<<<dim3(6, (VV + 127) / 128), 256, 0, stream>>>(vb, Wb, vW, VV, 768, KEP);

    // 3) leaves
    k_leaf<<<BT * 64 / 4, 256, 0, stream>>>(tok, vW, qD, b, h);

    // 4) fused per-level GEMM+update, lv=1..6 (cnl = 7-lv)
    for (int lv = 1; lv <= 6; ++lv) {
        int cnl = 7 - lv;
        int ncT = BT << cnl;
        k_lvl<<<ncT / 64, 512, 0, stream>>>(tok, dep, vW, qD, b, Ub, h,
                                            (lv == 6) ? (float*)d_out : nullptr, cnl);
    }
}

// Round 13
// 235.212 us; speedup vs baseline: 1.4043x; 1.0630x over previous
//
#include <hip/hip_runtime.h>

typedef unsigned short u16;
typedef u16 u16x4 __attribute__((ext_vector_type(4)));
typedef u16 u16x8 __attribute__((ext_vector_type(8)));
typedef __bf16 bf16x8 __attribute__((ext_vector_type(8)));
typedef float f32x4 __attribute__((ext_vector_type(4)));

#define HB   256    // H
#define NND  127    // nodes per tree
#define BT   512    // trees (batch)
#define KE   300    // E
#define KEP  320    // E padded to 32-multiple
#define VV   50000  // vocab
#define QQ   10     // Q

#define AS1 __attribute__((address_space(1)))
#define AS3 __attribute__((address_space(3)))

__device__ __forceinline__ u16 f2bf(float f) {
    unsigned int u = __builtin_bit_cast(unsigned int, f);
    u += 0x7FFFu + ((u >> 16) & 1u);          // RNE
    return (u16)(u >> 16);
}
__device__ __forceinline__ float bf2f(u16 h) {
    unsigned int u = ((unsigned int)h) << 16;
    return __builtin_bit_cast(float, u);
}
__device__ __forceinline__ float sigm(float x) { return 1.f / (1.f + __expf(-x)); }

__device__ __forceinline__ void glds16(const u16* g, u16* l) {
    __builtin_amdgcn_global_load_lds((const AS1 void*)g, (AS3 void*)l, 16, 0, 0);
}

// ---------- merged prep: vocab conv (15625 blks), W (120), U (96), qD (30) ----------
__global__ __launch_bounds__(256) void k_prep(const float* __restrict__ vec,
                                              u16* __restrict__ vb,
                                              const float* __restrict__ W,
                                              const float* __restrict__ U,
                                              const float* __restrict__ q,
                                              const float* __restrict__ D,
                                              u16* __restrict__ Wb,
                                              u16* __restrict__ Ub,
                                              float* __restrict__ qD) {
    int blk = blockIdx.x;
    if (blk < 15625) {                     // vec: VV rows, K=300 -> Kp=320, u16x4 chunks
        long i = (long)blk * 256 + threadIdx.x;   // 4,000,000 chunks exactly
        int r = (int)(i / 80);
        int c = ((int)(i - (long)r * 80)) * 4;
        u16x4 o = {0, 0, 0, 0};
        if (c < KE) {
            f32x4 x = *(const f32x4*)(vec + (long)r * KE + c);
#pragma unroll
            for (int e = 0; e < 4; ++e) o[e] = f2bf(x[e]);
        }
        *(u16x4*)(vb + i * 4) = o;
    } else if (blk < 15745) {              // W: 768 rows, K=300 -> Kp=320 (40 chunks)
        int i = (blk - 15625) * 256 + threadIdx.x;
        int r = i / 40, c = (i - r * 40) * 8;
        const float* s = W + (long)r * KE + c;
        u16x8 o;
#pragma unroll
        for (int e = 0; e < 8; ++e) o[e] = (c + e < KE) ? f2bf(s[e]) : (u16)0;
        *(u16x8*)(Wb + (long)i * 8) = o;
    } else if (blk < 15841) {              // U: 768 rows, K=Kp=256 (32 chunks)
        int i = (blk - 15745) * 256 + threadIdx.x;
        int r = i / 32, c = (i - r * 32) * 8;
        const float* s = U + (long)r * HB + c;
        u16x8 o;
#pragma unroll
        for (int e = 0; e < 8; ++e) o[e] = f2bf(s[e]);
        *(u16x8*)(Ub + (long)i * 8) = o;
    } else {                               // qD[i] over QQ*768
        int i = (blk - 15841) * 256 + threadIdx.x;
        int qi = i / 768, col = i - qi * 768;
        const float* qr = q + qi * HB;
        const float* dr = D + col * HB;
        float s = 0.f;
        for (int k = 0; k < HB; ++k) s += qr[k] * dr[k];
        qD[i] = s;
    }
}

// ---------- bf16 NT GEMM: global_load_lds(16B), 128x128 tile ----------
// Depth-3 pipeline, 4 LDS buffers, counted vmcnt (T4) — frozen (R6).
// optional A-row map: global_row = (r>>cnlog2)*127 + cstart + (r & ((1<<cnlog2)-1))
template <bool STORE_BF16>
__global__ __launch_bounds__(256) void k_gemm(const u16* __restrict__ A,
                                              const u16* __restrict__ B,
                                              void* __restrict__ C,
                                              int M, int N, int K,
                                              int map_cnlog2, int map_cstart) {
    __shared__ u16 As[4][128 * 32];
    __shared__ u16 Bs[4][128 * 32];

    int nwg = gridDim.x * gridDim.y;
    int orig = blockIdx.y * gridDim.x + blockIdx.x;
    int qq = nwg >> 3, rr = nwg & 7;
    int xcd = orig & 7, cidx = orig >> 3;
    int wg = (xcd < rr ? xcd * (qq + 1) : rr * (qq + 1) + (xcd - rr) * qq) + cidx;
    int bx = wg % gridDim.x, by = wg / gridDim.x;
    int row0 = by * 128, col0 = bx * 128;

    int t = threadIdx.x, lane = t & 63, w = t >> 6;
    int wr = w >> 1, wc = w & 1;

    int cof = (lane & 3) * 8;            // u16 col offset
    int rin = lane >> 2;                 // 0..15 row within issue
    int ar0 = row0 + w * 32 + rin;
    int ar1 = ar0 + 16;
    auto mapfn = [&](int r) {
        if (r > M - 1) r = M - 1;
        if (map_cnlog2 >= 0) {
            int bt = r >> map_cnlog2;
            int of = r & ((1 << map_cnlog2) - 1);
            r = bt * NND + map_cstart + of;
        }
        return r;
    };
    const u16* aS0 = A + (long)mapfn(ar0) * K + cof;
    const u16* aS1 = A + (long)mapfn(ar1) * K + cof;
    const u16* bS0 = B + (long)(col0 + w * 32 + rin) * K + cof;
    const u16* bS1 = bS0 + 16L * K;
    int dof0 = (w * 32) * 32;
    int dof1 = (w * 32 + 16) * 32;

    f32x4 acc[4][4];
#pragma unroll
    for (int m = 0; m < 4; ++m)
#pragma unroll
        for (int n = 0; n < 4; ++n) acc[m][n] = f32x4{0.f, 0.f, 0.f, 0.f};

    int arl = wr * 64 + (lane & 15);
    int brl = wc * 64 + (lane & 15);
    int kk = (lane >> 4) * 8;

    auto stage = [&](int sel, int ko) {
        glds16(aS0 + ko, &As[sel][dof0]);
        glds16(aS1 + ko, &As[sel][dof1]);
        glds16(bS0 + ko, &Bs[sel][dof0]);
        glds16(bS1 + ko, &Bs[sel][dof1]);
    };
    auto compute = [&](int sel) {
        bf16x8 af[4], bfr[4];
#pragma unroll
        for (int m = 0; m < 4; ++m)
            af[m] = *(const bf16x8*)&As[sel][(arl + m * 16) * 32 + kk];
#pragma unroll
        for (int n = 0; n < 4; ++n)
            bfr[n] = *(const bf16x8*)&Bs[sel][(brl + n * 16) * 32 + kk];
#pragma unroll
        for (int m = 0; m < 4; ++m)
#pragma unroll
            for (int n = 0; n < 4; ++n)
                acc[m][n] = __builtin_amdgcn_mfma_f32_16x16x32_bf16(af[m], bfr[n], acc[m][n], 0, 0, 0);
    };

    int nk = K >> 5;
    stage(0, 0); stage(1, 32); stage(2, 64);
    for (int kt = 0; kt < nk - 3; ++kt) {
        asm volatile("s_waitcnt vmcnt(8)" ::: "memory");
        __builtin_amdgcn_s_barrier();
        __builtin_amdgcn_sched_barrier(0);
        compute(kt & 3);
        stage((kt + 3) & 3, (kt + 3) * 32);
    }
    asm volatile("s_waitcnt vmcnt(8)" ::: "memory");
    __builtin_amdgcn_s_barrier();
    __builtin_amdgcn_sched_barrier(0);
    compute((nk - 3) & 3);
    asm volatile("s_waitcnt vmcnt(4)" ::: "memory");
    __builtin_amdgcn_s_barrier();
    __builtin_amdgcn_sched_barrier(0);
    compute((nk - 2) & 3);
    asm volatile("s_waitcnt vmcnt(0)" ::: "memory");
    __builtin_amdgcn_s_barrier();
    __builtin_amdgcn_sched_barrier(0);
    compute((nk - 1) & 3);

    int crow = row0 + wr * 64 + (lane >> 4) * 4;
    int ccol = col0 + wc * 64 + (lane & 15);
#pragma unroll
    for (int m = 0; m < 4; ++m) {
#pragma unroll
        for (int n = 0; n < 4; ++n) {
#pragma unroll
            for (int j = 0; j < 4; ++j) {
                int r = crow + m * 16 + j;
                int c = ccol + n * 16;
                if (r < M) {
                    if (STORE_BF16) ((u16*)C)[(long)r * N + c] = f2bf(acc[m][n][j]);
                    else            ((float*)C)[(long)r * N + c] = acc[m][n][j];
                }
            }
        }
    }
}

// ---------- leaves, vectorized: one wave per leaf, 4 j per lane ----------
__global__ __launch_bounds__(256) void k_leaf(const int* __restrict__ tok,
                                              const u16* __restrict__ vW,
                                              const float* __restrict__ qD,
                                              const float* __restrict__ b,
                                              u16* __restrict__ h) {
    int w = threadIdx.x >> 6, t = threadIdx.x & 63;
    int leaf = blockIdx.x * 4 + w;             // 0..32767
    int j = t * 4;
    int bt = leaf >> 6, li = leaf & 63;        // 64 leaves per tree
    int row = bt * NND + 63 + li;
    long vwb = (long)tok[row] * 768;
    u16x4 vi = *(const u16x4*)(vW + vwb + 256 + j);
    u16x4 vu = *(const u16x4*)(vW + vwb + 512 + j);
    f32x4 qi = *(const f32x4*)(qD + 9 * 768 + 256 + j);
    f32x4 qu = *(const f32x4*)(qD + 9 * 768 + 512 + j);
    f32x4 bi = *(const f32x4*)(b + 256 + j);
    f32x4 bu = *(const f32x4*)(b + 512 + j);
    u16x4 o;
#pragma unroll
    for (int e = 0; e < 4; ++e) {
        float ii = bf2f(vi[e]) + qi[e] + bi[e];
        float uu = bf2f(vu[e]) + qu[e] + bu[e];
        o[e] = f2bf(tanhf(sigm(ii) * tanhf(uu)));
    }
    *(u16x4*)(h + (long)row * HB + j) = o;
}

// ---------- lv1 update, vectorized: one wave per parent, 4 j per lane ----------
__global__ __launch_bounds__(256) void k_update(const int* __restrict__ tok,
                                                const int* __restrict__ dep,
                                                const u16* __restrict__ vW,
                                                const float* __restrict__ qD,
                                                const float* __restrict__ b,
                                                const u16* __restrict__ g,
                                                u16* __restrict__ h,
                                                int pstart, int pnl) {
    int w = threadIdx.x >> 6, t = threadIdx.x & 63;
    int pi = blockIdx.x * 4 + w;
    int j = t * 4;
    int bt = pi >> pnl, po = pi & ((1 << pnl) - 1);
    int pl = pstart + po;
    int gp  = bt * NND + pl;
    int gc1 = bt * NND + 2 * pl + 1, gc2 = gc1 + 1;
    long cc1 = (long)((bt << (pnl + 1)) + 2 * po) * 768;
    long cc2 = cc1 + 768;
    long vwb = (long)tok[gp] * 768;
    int d1 = dep[gc1] * 768, d2 = dep[gc2] * 768;
    u16x4 vf  = *(const u16x4*)(vW + vwb + j);
    u16x4 vi  = *(const u16x4*)(vW + vwb + 256 + j);
    u16x4 vu  = *(const u16x4*)(vW + vwb + 512 + j);
    u16x4 gf1 = *(const u16x4*)(g + cc1 + j);
    u16x4 gf2 = *(const u16x4*)(g + cc2 + j);
    u16x4 gi1 = *(const u16x4*)(g + cc1 + 256 + j);
    u16x4 gi2 = *(const u16x4*)(g + cc2 + 256 + j);
    u16x4 gu1 = *(const u16x4*)(g + cc1 + 512 + j);
    u16x4 gu2 = *(const u16x4*)(g + cc2 + 512 + j);
    f32x4 qf1 = *(const f32x4*)(qD + d1 + j);
    f32x4 qf2 = *(const f32x4*)(qD + d2 + j);
    f32x4 qi1 = *(const f32x4*)(qD + d1 + 256 + j);
    f32x4 qi2 = *(const f32x4*)(qD + d2 + 256 + j);
    f32x4 qu1 = *(const f32x4*)(qD + d1 + 512 + j);
    f32x4 qu2 = *(const f32x4*)(qD + d2 + 512 + j);
    f32x4 bf_ = *(const f32x4*)(b + j);
    f32x4 bi_ = *(const f32x4*)(b + 256 + j);
    f32x4 bu_ = *(const f32x4*)(b + 512 + j);
    u16x4 h1v = *(const u16x4*)(h + (long)gc1 * HB + j);
    u16x4 h2v = *(const u16x4*)(h + (long)gc2 * HB + j);
    u16x4 resb;
#pragma unroll
    for (int e = 0; e < 4; ++e) {
        float xf = bf2f(vf[e]) + bf_[e];
        float f1 = sigm(xf + bf2f(gf1[e]) + qf1[e]);
        float f2 = sigm(xf + bf2f(gf2[e]) + qf2[e]);
        float ii = bf2f(vi[e]) + bf2f(gi1[e]) + bf2f(gi2[e]) + qi1[e] + qi2[e] + bi_[e];
        float uu = bf2f(vu[e]) + bf2f(gu1[e]) + bf2f(gu2[e]) + qu1[e] + qu2[e] + bu_[e];
        float hn = tanhf(sigm(ii) * tanhf(uu) + f1 * bf2f(h1v[e]) + f2 * bf2f(h2v[e]));
        resb[e] = f2bf(hn);
    }
    *(u16x4*)(h + (long)gp * HB + j) = resb;
}

// ---------- fused per-level GEMM + update (lv2..6) ----------
// Block (512 thr / 8 waves) owns 64 child rows (= 32 parents) x all 768 cols.
// GEMM phase == R12 (proven); then acc -> LDS (gf bf16, giu fp32-pair-summed),
// then coalesced update phase (one wave per parent, j = lane*4, g from LDS).
__global__ __launch_bounds__(512) void k_lvl(const int* __restrict__ tok,
                                             const int* __restrict__ dep,
                                             const u16* __restrict__ vW,
                                             const float* __restrict__ qD,
                                             const float* __restrict__ b,
                                             const u16* __restrict__ Ub,
                                             u16* __restrict__ h,
                                             float* __restrict__ out,
                                             int cnl) {
    __shared__ u16 smem[32768];      // 64 KB union: K-loop {Bs 24576, As 2048} / epi {gf 16384, giu 16384}
    u16* BsL = smem;
    u16* AsL = smem + 24576;

    int cn = 1 << cnl, cstart = cn - 1;
    int pnl = cnl - 1, pn = 1 << pnl, pstart = pn - 1;
    int blk = blockIdx.x;
    int t = threadIdx.x, lane = t & 63, w = t >> 6;
    int rin = lane >> 2, cof = (lane & 3) * 8;
    int kk = (lane >> 4) * 8;
    int l15 = lane & 15;

    int rhA = blk * 64 + w * 16 + rin;
    int btA = rhA >> cnl;
    const u16* aSrc = h + (long)(btA * NND + cstart + (rhA & (cn - 1))) * HB + cof;
    const u16* bSrc = Ub + (long)(w * 16 + rin) * HB + cof;

    f32x4 acc[4][6];
#pragma unroll
    for (int m = 0; m < 4; ++m)
#pragma unroll
        for (int f = 0; f < 6; ++f) acc[m][f] = f32x4{0.f, 0.f, 0.f, 0.f};

    for (int ks = 0; ks < 8; ++ks) {
        __syncthreads();
        if (w < 4) glds16(aSrc + ks * 32, &AsL[(w * 16) * 32]);
#pragma unroll
        for (int is = 0; is < 6; ++is)
            glds16(bSrc + (long)is * 128 * HB + ks * 32, &BsL[(is * 128 + w * 16) * 32]);
        __syncthreads();
        bf16x8 af[4], bf[6];
#pragma unroll
        for (int m = 0; m < 4; ++m)
            af[m] = *(const bf16x8*)&AsL[(m * 16 + l15) * 32 + kk];
#pragma unroll
        for (int f = 0; f < 6; ++f) {
            int part = f >> 1, within = f & 1;
            int brow = part * 256 + w * 32 + within * 16 + l15;
            bf[f] = *(const bf16x8*)&BsL[brow * 32 + kk];
        }
#pragma unroll
        for (int m = 0; m < 4; ++m)
#pragma unroll
            for (int f = 0; f < 6; ++f)
                acc[m][f] = __builtin_amdgcn_mfma_f32_16x16x32_bf16(af[m], bf[f], acc[m][f], 0, 0, 0);
    }

    // ---- epilogue: acc -> LDS (alias As/Bs after barrier) ----
    __syncthreads();
    u16* gfL  = smem;            // [64][256]
    u16* giuL = smem + 16384;    // [32][512]  (i at 0..255, u at 256..511)
#pragma unroll
    for (int m = 0; m < 4; ++m) {
        int r0 = m * 16 + (lane >> 4) * 4;
#pragma unroll
        for (int within = 0; within < 2; ++within) {
            int c = w * 32 + within * 16 + l15;
#pragma unroll
            for (int j = 0; j < 4; ++j)
                gfL[(r0 + j) * 256 + c] = f2bf(acc[m][within][j]);
            int pb0 = r0 >> 1;
            giuL[pb0 * 512 + c]           = f2bf(acc[m][2 + within][0] + acc[m][2 + within][1]);
            giuL[(pb0 + 1) * 512 + c]     = f2bf(acc[m][2 + within][2] + acc[m][2 + within][3]);
            giuL[pb0 * 512 + 256 + c]     = f2bf(acc[m][4 + within][0] + acc[m][4 + within][1]);
            giuL[(pb0 + 1) * 512 + 256 + c] = f2bf(acc[m][4 + within][2] + acc[m][4 + within][3]);
        }
    }
    __syncthreads();

    // ---- update phase: 4 passes x 8 waves = 32 parents; j = lane*4 ----
    int j = lane * 4;
#pragma unroll
    for (int pp = 0; pp < 4; ++pp) {
        int pb = pp * 8 + w;
        int pi = blk * 32 + pb;
        int bt = pi >> pnl;
        int po = pi & (pn - 1);
        int gp  = bt * NND + pstart + po;
        int gc1 = bt * NND + cstart + 2 * po, gc2 = gc1 + 1;
        long vwb = (long)tok[gp] * 768;
        int d1 = dep[gc1] * 768, d2 = dep[gc2] * 768;
        u16x4 vf  = *(const u16x4*)(vW + vwb + j);
        u16x4 vi  = *(const u16x4*)(vW + vwb + 256 + j);
        u16x4 vu  = *(const u16x4*)(vW + vwb + 512 + j);
        u16x4 gf1 = *(const u16x4*)&gfL[(2 * pb) * 256 + j];
        u16x4 gf2 = *(const u16x4*)&gfL[(2 * pb + 1) * 256 + j];
        u16x4 gis = *(const u16x4*)&giuL[pb * 512 + j];
        u16x4 gus = *(const u16x4*)&giuL[pb * 512 + 256 + j];
        f32x4 qf1 = *(const f32x4*)(qD + d1 + j);
        f32x4 qf2 = *(const f32x4*)(qD + d2 + j);
        f32x4 qi1 = *(const f32x4*)(qD + d1 + 256 + j);
        f32x4 qi2 = *(const f32x4*)(qD + d2 + 256 + j);
        f32x4 qu1 = *(const f32x4*)(qD + d1 + 512 + j);
        f32x4 qu2 = *(const f32x4*)(qD + d2 + 512 + j);
        f32x4 bf_ = *(const f32x4*)(b + j);
        f32x4 bi_ = *(const f32x4*)(b + 256 + j);
        f32x4 bu_ = *(const f32x4*)(b + 512 + j);
        u16x4 h1v = *(const u16x4*)(h + (long)gc1 * HB + j);
        u16x4 h2v = *(const u16x4*)(h + (long)gc2 * HB + j);
        u16x4 resb;
        f32x4 resf;
#pragma unroll
        for (int e = 0; e < 4; ++e) {
            float xf = bf2f(vf[e]) + bf_[e];
            float f1 = sigm(xf + bf2f(gf1[e]) + qf1[e]);
            float f2 = sigm(xf + bf2f(gf2[e]) + qf2[e]);
            float ii = bf2f(vi[e]) + bf2f(gis[e]) + qi1[e] + qi2[e] + bi_[e];
            float uu = bf2f(vu[e]) + bf2f(gus[e]) + qu1[e] + qu2[e] + bu_[e];
            float hn = tanhf(sigm(ii) * tanhf(uu) + f1 * bf2f(h1v[e]) + f2 * bf2f(h2v[e]));
            resf[e] = hn;
            resb[e] = f2bf(hn);
        }
        if (out) *(f32x4*)(out + (long)bt * HB + j) = resf;   // lv6: pn==1 -> pi==bt
        else     *(u16x4*)(h + (long)gp * HB + j) = resb;
    }
}

extern "C" void kernel_launch(void* const* d_in, const int* in_sizes, int n_in,
                              void* d_out, int out_size, void* d_ws, size_t ws_size,
                              hipStream_t stream) {
    const int*   tok = (const int*)d_in[0];
    const int*   dep = (const int*)d_in[1];
    const float* vec = (const float*)d_in[2];
    const float* q   = (const float*)d_in[3];
    const float* W   = (const float*)d_in[4];
    const float* U   = (const float*)d_in[5];
    const float* D   = (const float*)d_in[6];
    const float* b   = (const float*)d_in[7];

    char* ws = (char*)d_ws;
    size_t off = 0;
    auto alloc = [&](size_t bytes) {
        void* p = ws + off;
        off += (bytes + 255) & ~(size_t)255;
        return p;
    };
    float* qD = (float*)alloc((size_t)QQ * 768 * 4);
    u16*   vb = (u16*)alloc((size_t)VV * KEP * 2);
    u16*   Wb = (u16*)alloc((size_t)768 * KEP * 2);
    u16*   Ub = (u16*)alloc((size_t)768 * HB * 2);
    u16*   vW = (u16*)alloc((size_t)VV * 768 * 2);
    u16*   h  = (u16*)alloc((size_t)BT * NND * HB * 2);
    u16*   g  = (u16*)alloc((size_t)BT * 64 * 768 * 2);   // lv1 only
    if (ws_size < off) return;  // ~177 MiB needed; zero output signals ws too small

    // 1) prep
    k_prep<<<15871, 256, 0, stream>>>(vec, vb, W, U, q, D, Wb, Ub, qD);

    // 2) vW = (idx2vec @ W.T) bf16
    k_gemm<true><<<dim3(6, (VV + 127) / 128), 256, 0, stream>>>(
        vb, Wb, vW, VV, 768, KEP, -1, 0);

    // 3) leaves
    k_leaf<<<BT * 64 / 4, 256, 0, stream>>>(tok, vW, qD, b, h);

    // 4) lv1: proven split path
    k_gemm<true><<<dim3(6, 256), 256, 0, stream>>>(
        h, Ub, g, BT * 64, 768, HB, 6, 63);
    k_update<<<BT * 32 / 4, 256, 0, stream>>>(tok, dep, vW, qD, b, g, h, 31, 5);

    // 5) lv2..6 fused (cnl = 7-lv)
    for (int lv = 2; lv <= 6; ++lv) {
        int cnl = 7 - lv;
        int ncT = BT << cnl;
        k_lvl<<<ncT / 64, 512, 0, stream>>>(tok, dep, vW, qD, b, Ub, h,
                                            (lv == 6) ? (float*)d_out : nullptr, cnl);
    }
}

// Round 14
// 209.696 us; speedup vs baseline: 1.5752x; 1.1217x over previous
//
#include <hip/hip_runtime.h>

typedef unsigned short u16;
typedef u16 u16x4 __attribute__((ext_vector_type(4)));
typedef u16 u16x8 __attribute__((ext_vector_type(8)));
typedef __bf16 bf16x8 __attribute__((ext_vector_type(8)));
typedef float f32x4 __attribute__((ext_vector_type(4)));

#define HB   256    // H
#define NND  127    // nodes per tree
#define BT   512    // trees (batch)
#define KE   300    // E
#define KEP  320    // E padded to 32-multiple
#define VV   50000  // vocab
#define QQ   10     // Q

#define AS1 __attribute__((address_space(1)))
#define AS3 __attribute__((address_space(3)))

__device__ __forceinline__ u16 f2bf(float f) {
    unsigned int u = __builtin_bit_cast(unsigned int, f);
    u += 0x7FFFu + ((u >> 16) & 1u);          // RNE
    return (u16)(u >> 16);
}
__device__ __forceinline__ float bf2f(u16 h) {
    unsigned int u = ((unsigned int)h) << 16;
    return __builtin_bit_cast(float, u);
}
__device__ __forceinline__ float sigm(float x) { return 1.f / (1.f + __expf(-x)); }

__device__ __forceinline__ void glds16(const u16* g, u16* l) {
    __builtin_amdgcn_global_load_lds((const AS1 void*)g, (AS3 void*)l, 16, 0, 0);
}

// ---------- merged prep: vocab conv (15625 blks), W (120), U (96), qD (30) ----------
__global__ __launch_bounds__(256) void k_prep(const float* __restrict__ vec,
                                              u16* __restrict__ vb,
                                              const float* __restrict__ W,
                                              const float* __restrict__ U,
                                              const float* __restrict__ q,
                                              const float* __restrict__ D,
                                              u16* __restrict__ Wb,
                                              u16* __restrict__ Ub,
                                              float* __restrict__ qD) {
    int blk = blockIdx.x;
    if (blk < 15625) {                     // vec: VV rows, K=300 -> Kp=320, u16x4 chunks
        long i = (long)blk * 256 + threadIdx.x;   // 4,000,000 chunks exactly
        int r = (int)(i / 80);
        int c = ((int)(i - (long)r * 80)) * 4;
        u16x4 o = {0, 0, 0, 0};
        if (c < KE) {
            f32x4 x = *(const f32x4*)(vec + (long)r * KE + c);
#pragma unroll
            for (int e = 0; e < 4; ++e) o[e] = f2bf(x[e]);
        }
        *(u16x4*)(vb + i * 4) = o;
    } else if (blk < 15745) {              // W: 768 rows, K=300 -> Kp=320 (40 chunks)
        int i = (blk - 15625) * 256 + threadIdx.x;
        int r = i / 40, c = (i - r * 40) * 8;
        const float* s = W + (long)r * KE + c;
        u16x8 o;
#pragma unroll
        for (int e = 0; e < 8; ++e) o[e] = (c + e < KE) ? f2bf(s[e]) : (u16)0;
        *(u16x8*)(Wb + (long)i * 8) = o;
    } else if (blk < 15841) {              // U: 768 rows, K=Kp=256 (32 chunks)
        int i = (blk - 15745) * 256 + threadIdx.x;
        int r = i / 32, c = (i - r * 32) * 8;
        const float* s = U + (long)r * HB + c;
        u16x8 o;
#pragma unroll
        for (int e = 0; e < 8; ++e) o[e] = f2bf(s[e]);
        *(u16x8*)(Ub + (long)i * 8) = o;
    } else {                               // qD[i] over QQ*768
        int i = (blk - 15841) * 256 + threadIdx.x;
        int qi = i / 768, col = i - qi * 768;
        const float* qr = q + qi * HB;
        const float* dr = D + col * HB;
        float s = 0.f;
        for (int k = 0; k < HB; ++k) s += qr[k] * dr[k];
        qD[i] = s;
    }
}

// ---------- bf16 NT GEMM: global_load_lds(16B), 128x128 tile ----------
// Depth-3 pipeline, 4 LDS buffers, counted vmcnt (T4) — best measured variant (R6), frozen.
// C[M,N] = A[M,K] * B[N,K]^T ; A,B bf16 row-major, K/32 = nk >= 4, N % 128 == 0.
// optional A-row map: global_row = (r>>cnlog2)*127 + cstart + (r & ((1<<cnlog2)-1))
template <bool STORE_BF16>
__global__ __launch_bounds__(256) void k_gemm(const u16* __restrict__ A,
                                              const u16* __restrict__ B,
                                              void* __restrict__ C,
                                              int M, int N, int K,
                                              int map_cnlog2, int map_cstart) {
    __shared__ u16 As[4][128 * 32];
    __shared__ u16 Bs[4][128 * 32];

    // bijective XCD-chunked swizzle (m204) on linear bid, x-inner
    int nwg = gridDim.x * gridDim.y;
    int orig = blockIdx.y * gridDim.x + blockIdx.x;
    int qq = nwg >> 3, rr = nwg & 7;
    int xcd = orig & 7, cidx = orig >> 3;
    int wg = (xcd < rr ? xcd * (qq + 1) : rr * (qq + 1) + (xcd - rr) * qq) + cidx;
    int bx = wg % gridDim.x, by = wg / gridDim.x;
    int row0 = by * 128, col0 = bx * 128;

    int t = threadIdx.x, lane = t & 63, w = t >> 6;
    int wr = w >> 1, wc = w & 1;

    // staging geometry: per wave-issue, 64 lanes x 16B = 16 rows x 32 u16
    int cof = (lane & 3) * 8;            // u16 col offset
    int rin = lane >> 2;                 // 0..15 row within issue
    int ar0 = row0 + w * 32 + rin;
    int ar1 = ar0 + 16;
    auto mapfn = [&](int r) {
        if (r > M - 1) r = M - 1;
        if (map_cnlog2 >= 0) {
            int bt = r >> map_cnlog2;
            int of = r & ((1 << map_cnlog2) - 1);
            r = bt * NND + map_cstart + of;
        }
        return r;
    };
    const u16* aS0 = A + (long)mapfn(ar0) * K + cof;
    const u16* aS1 = A + (long)mapfn(ar1) * K + cof;
    const u16* bS0 = B + (long)(col0 + w * 32 + rin) * K + cof;
    const u16* bS1 = bS0 + 16L * K;
    int dof0 = (w * 32) * 32;
    int dof1 = (w * 32 + 16) * 32;

    f32x4 acc[4][4];
#pragma unroll
    for (int m = 0; m < 4; ++m)
#pragma unroll
        for (int n = 0; n < 4; ++n) acc[m][n] = f32x4{0.f, 0.f, 0.f, 0.f};

    int arl = wr * 64 + (lane & 15);
    int brl = wc * 64 + (lane & 15);
    int kk = (lane >> 4) * 8;

    auto stage = [&](int sel, int ko) {
        glds16(aS0 + ko, &As[sel][dof0]);
        glds16(aS1 + ko, &As[sel][dof1]);
        glds16(bS0 + ko, &Bs[sel][dof0]);
        glds16(bS1 + ko, &Bs[sel][dof1]);
    };
    auto compute = [&](int sel) {
        bf16x8 af[4], bfr[4];
#pragma unroll
        for (int m = 0; m < 4; ++m)
            af[m] = *(const bf16x8*)&As[sel][(arl + m * 16) * 32 + kk];
#pragma unroll
        for (int n = 0; n < 4; ++n)
            bfr[n] = *(const bf16x8*)&Bs[sel][(brl + n * 16) * 32 + kk];
#pragma unroll
        for (int m = 0; m < 4; ++m)
#pragma unroll
            for (int n = 0; n < 4; ++n)
                acc[m][n] = __builtin_amdgcn_mfma_f32_16x16x32_bf16(af[m], bfr[n], acc[m][n], 0, 0, 0);
    };

    int nk = K >> 5;                     // 8 or 10 here (>= 4 required)
    stage(0, 0); stage(1, 32); stage(2, 64);     // 12 loads/wave in flight
    for (int kt = 0; kt < nk - 3; ++kt) {
        asm volatile("s_waitcnt vmcnt(8)" ::: "memory");
        __builtin_amdgcn_s_barrier();
        __builtin_amdgcn_sched_barrier(0);
        compute(kt & 3);
        stage((kt + 3) & 3, (kt + 3) * 32);
    }
    asm volatile("s_waitcnt vmcnt(8)" ::: "memory");
    __builtin_amdgcn_s_barrier();
    __builtin_amdgcn_sched_barrier(0);
    compute((nk - 3) & 3);
    asm volatile("s_waitcnt vmcnt(4)" ::: "memory");
    __builtin_amdgcn_s_barrier();
    __builtin_amdgcn_sched_barrier(0);
    compute((nk - 2) & 3);
    asm volatile("s_waitcnt vmcnt(0)" ::: "memory");
    __builtin_amdgcn_s_barrier();
    __builtin_amdgcn_sched_barrier(0);
    compute((nk - 1) & 3);

    int crow = row0 + wr * 64 + (lane >> 4) * 4;
    int ccol = col0 + wc * 64 + (lane & 15);
#pragma unroll
    for (int m = 0; m < 4; ++m) {
#pragma unroll
        for (int n = 0; n < 4; ++n) {
#pragma unroll
            for (int j = 0; j < 4; ++j) {
                int r = crow + m * 16 + j;
                int c = ccol + n * 16;
                if (r < M) {
                    if (STORE_BF16) ((u16*)C)[(long)r * N + c] = f2bf(acc[m][n][j]);
                    else            ((float*)C)[(long)r * N + c] = acc[m][n][j];
                }
            }
        }
    }
}

// ---------- leaves, vectorized: one wave per leaf, 4 j per lane ----------
__global__ __launch_bounds__(256) void k_leaf(const int* __restrict__ tok,
                                              const u16* __restrict__ vW,
                                              const float* __restrict__ qD,
                                              const float* __restrict__ b,
                                              u16* __restrict__ h) {
    int w = threadIdx.x >> 6, t = threadIdx.x & 63;
    int leaf = blockIdx.x * 4 + w;             // 0..32767
    int j = t * 4;
    int bt = leaf >> 6, li = leaf & 63;        // 64 leaves per tree
    int row = bt * NND + 63 + li;
    long vwb = (long)tok[row] * 768;
    u16x4 vi = *(const u16x4*)(vW + vwb + 256 + j);
    u16x4 vu = *(const u16x4*)(vW + vwb + 512 + j);
    f32x4 qi = *(const f32x4*)(qD + 9 * 768 + 256 + j);
    f32x4 qu = *(const f32x4*)(qD + 9 * 768 + 512 + j);
    f32x4 bi = *(const f32x4*)(b + 256 + j);
    f32x4 bu = *(const f32x4*)(b + 512 + j);
    u16x4 o;
#pragma unroll
    for (int e = 0; e < 4; ++e) {
        float ii = bf2f(vi[e]) + qi[e] + bi[e];
        float uu = bf2f(vu[e]) + qu[e] + bu[e];
        o[e] = f2bf(tanhf(sigm(ii) * tanhf(uu)));
    }
    *(u16x4*)(h + (long)row * HB + j) = o;
}

// ---------- per-level update, vectorized: one wave per parent, 4 j per lane ----------
// g row layout per child c (compact level order): [0:256]=f-part, [256:512]=i, [512:768]=u
__global__ __launch_bounds__(256) void k_update(const int* __restrict__ tok,
                                                const int* __restrict__ dep,
                                                const u16* __restrict__ vW,
                                                const float* __restrict__ qD,
                                                const float* __restrict__ b,
                                                const u16* __restrict__ g,
                                                u16* __restrict__ h,
                                                float* __restrict__ out,
                                                int pstart, int pnl) {
    int w = threadIdx.x >> 6, t = threadIdx.x & 63;
    int pi = blockIdx.x * 4 + w;
    int j = t * 4;
    int bt = pi >> pnl, po = pi & ((1 << pnl) - 1);
    int pl = pstart + po;
    int gp  = bt * NND + pl;
    int gc1 = bt * NND + 2 * pl + 1, gc2 = gc1 + 1;
    long cc1 = (long)((bt << (pnl + 1)) + 2 * po) * 768;  // g rows of the two children
    long cc2 = cc1 + 768;
    long vwb = (long)tok[gp] * 768;
    int d1 = dep[gc1] * 768, d2 = dep[gc2] * 768;
    u16x4 vf  = *(const u16x4*)(vW + vwb + j);
    u16x4 vi  = *(const u16x4*)(vW + vwb + 256 + j);
    u16x4 vu  = *(const u16x4*)(vW + vwb + 512 + j);
    u16x4 gf1 = *(const u16x4*)(g + cc1 + j);
    u16x4 gf2 = *(const u16x4*)(g + cc2 + j);
    u16x4 gi1 = *(const u16x4*)(g + cc1 + 256 + j);
    u16x4 gi2 = *(const u16x4*)(g + cc2 + 256 + j);
    u16x4 gu1 = *(const u16x4*)(g + cc1 + 512 + j);
    u16x4 gu2 = *(const u16x4*)(g + cc2 + 512 + j);
    f32x4 qf1 = *(const f32x4*)(qD + d1 + j);
    f32x4 qf2 = *(const f32x4*)(qD + d2 + j);
    f32x4 qi1 = *(const f32x4*)(qD + d1 + 256 + j);
    f32x4 qi2 = *(const f32x4*)(qD + d2 + 256 + j);
    f32x4 qu1 = *(const f32x4*)(qD + d1 + 512 + j);
    f32x4 qu2 = *(const f32x4*)(qD + d2 + 512 + j);
    f32x4 bf_ = *(const f32x4*)(b + j);
    f32x4 bi_ = *(const f32x4*)(b + 256 + j);
    f32x4 bu_ = *(const f32x4*)(b + 512 + j);
    u16x4 h1v = *(const u16x4*)(h + (long)gc1 * HB + j);
    u16x4 h2v = *(const u16x4*)(h + (long)gc2 * HB + j);
    f32x4 res;
    u16x4 resb;
#pragma unroll
    for (int e = 0; e < 4; ++e) {
        float xf = bf2f(vf[e]) + bf_[e];
        float f1 = sigm(xf + bf2f(gf1[e]) + qf1[e]);
        float f2 = sigm(xf + bf2f(gf2[e]) + qf2[e]);
        float ii = bf2f(vi[e]) + bf2f(gi1[e]) + bf2f(gi2[e]) + qi1[e] + qi2[e] + bi_[e];
        float uu = bf2f(vu[e]) + bf2f(gu1[e]) + bf2f(gu2[e]) + qu1[e] + qu2[e] + bu_[e];
        float hn = tanhf(sigm(ii) * tanhf(uu) + f1 * bf2f(h1v[e]) + f2 * bf2f(h2v[e]));
        res[e] = hn;
        resb[e] = f2bf(hn);
    }
    if (out) *(f32x4*)(out + (long)pi * HB + j) = res;     // lv6: pi == bt, fp32 output
    else     *(u16x4*)(h + (long)gp * HB + j) = resb;
}

extern "C" void kernel_launch(void* const* d_in, const int* in_sizes, int n_in,
                              void* d_out, int out_size, void* d_ws, size_t ws_size,
                              hipStream_t stream) {
    const int*   tok = (const int*)d_in[0];
    const int*   dep = (const int*)d_in[1];
    const float* vec = (const float*)d_in[2];
    const float* q   = (const float*)d_in[3];
    const float* W   = (const float*)d_in[4];
    const float* U   = (const float*)d_in[5];
    const float* D   = (const float*)d_in[6];
    const float* b   = (const float*)d_in[7];

    char* ws = (char*)d_ws;
    size_t off = 0;
    auto alloc = [&](size_t bytes) {
        void* p = ws + off;
        off += (bytes + 255) & ~(size_t)255;
        return p;
    };
    float* qD = (float*)alloc((size_t)QQ * 768 * 4);
    u16*   vb = (u16*)alloc((size_t)VV * KEP * 2);
    u16*   Wb = (u16*)alloc((size_t)768 * KEP * 2);
    u16*   Ub = (u16*)alloc((size_t)768 * HB * 2);
    u16*   vW = (u16*)alloc((size_t)VV * 768 * 2);
    u16*   h  = (u16*)alloc((size_t)BT * NND * HB * 2);
    u16*   g  = (u16*)alloc((size_t)BT * 64 * 768 * 2);
    if (ws_size < off) return;  // ~177 MiB needed; zero output signals ws too small

    // 1) prep: vocab conv + W/U conv + qD (merged, one dispatch)
    k_prep<<<15871, 256, 0, stream>>>(vec, vb, W, U, q, D, Wb, Ub, qD);

    // 2) vW = (idx2vec @ W.T) as bf16, vocab-wide
    k_gemm<true><<<dim3(6, (VV + 127) / 128), 256, 0, stream>>>(
        vb, Wb, vW, VV, 768, KEP, -1, 0);

    // 3) leaves
    k_leaf<<<BT * 64 / 4, 256, 0, stream>>>(tok, vW, qD, b, h);

    // 4) per-level split pipeline (measured best): g GEMM + update
    for (int lv = 1; lv <= 6; ++lv) {
        int pnl = 6 - lv;              // log2(parents per tree)
        int pn = 1 << pnl;
        int cnl = pnl + 1;             // log2(children per tree)
        int cstart = (1 << cnl) - 1;
        int npT = BT * pn, ncT = BT * (1 << cnl);
        k_gemm<true><<<dim3(6, ncT / 128), 256, 0, stream>>>(
            h, Ub, g, ncT, 768, HB, cnl, cstart);
        k_update<<<npT / 4, 256, 0, stream>>>(tok, dep, vW, qD, b, g, h,
                                              (lv == 6) ? (float*)d_out : nullptr,
                                              31 * 0 + (pn - 1), pnl);
    }
}